// Round 4
// baseline (111.750 us; speedup 1.0000x reference)
//
#include <hip/hip_runtime.h>

// PeriodicEmbedding: out[b, n*64+o] = relu( sum_i emb[b,n,i] * W[n,i,o] + bias[n,o] )
//   emb[b,n,i] = sin(2*pi*coef[n,i]*x[b,n])     i in [0,32)
//              = cos(2*pi*coef[n,i-32]*x[b,n])  i in [32,64)
// B=8192, N=256, D=64. Output f32 512 MB -> HBM-write-bound (~80 us fill-calibrated floor).
//
// History:
//  R0 108.8 us  LDS-staged, scalar stores.
//  R1 164.4 us  REGRESSION: ws-preconverted W, cold fragment loads on critical path.
//  R2 108.4 us  = R0: staging amortization + float4 stores worth ~0 -> limiter is the
//               aggregate write address stream, not instructions/staging/barriers.
//  R3: XCD-aware bid remap: XCD k owns tokens [32k,32k+32) per row-group, consecutive
//      same-XCD blocks cover consecutive n -> each XCD's concurrent writeback stream
//      tiles contiguous 8 KB per row (DRAM page locality), W+x slices L2-resident.

typedef short bf16x8 __attribute__((ext_vector_type(8)));
typedef float f32x4 __attribute__((ext_vector_type(4)));

#define BM    128   // rows per tile (4 waves x 32 rows)
#define TILES 4     // tiles per block -> 512 rows per block
#define LDW   72    // LDS row stride (bf16) for Wt: 144 B, keeps b128 16B-aligned

__device__ __forceinline__ short f2bf(float f) {
    unsigned u = __float_as_uint(f);
    unsigned r = (u + 0x7FFFu + ((u >> 16) & 1u)) >> 16;   // RNE
    return (short)r;
}

__global__ __launch_bounds__(256) void pe_kernel(
    const float* __restrict__ x,     // [B, N]
    const float* __restrict__ coef,  // [N, 32]
    const float* __restrict__ wgt,   // [N, 64, 64]  (i=k, o)
    const float* __restrict__ bias,  // [N, 64]
    float* __restrict__ out)         // [B, 16384]
{
    const int N = 256;

    // ---- XCD-aware remap: grid 4096 = 8 xcd * 32 n * 16 rowgrp ----
    // dispatch round-robins blockIdx across 8 XCDs; give XCD k a contiguous
    // 32-token span, consecutive same-XCD blocks -> consecutive n.
    const int bid = blockIdx.x;
    const int xcd = bid & 7;
    const int j   = bid >> 3;
    const int n      = xcd * 32 + (j & 31);
    const int b_base = (j >> 5) * (BM * TILES);

    __shared__ short wtl[64 * LDW];                   // Wt[o][k] bf16
    const int t = threadIdx.x;

    // ---- stage W[n] transposed into LDS as bf16 (once per block) ----
    const float* Wn = wgt + n * 4096;
    #pragma unroll
    for (int it = 0; it < 16; ++it) {
        int idx = it * 256 + t;                       // coalesced f32 read
        int i = idx >> 6, o = idx & 63;               // W[n][i][o]
        wtl[o * LDW + i] = f2bf(Wn[idx]);
    }
    __syncthreads();

    const int w  = t >> 6;
    const int l  = t & 63;
    const int lr = l & 15;
    const int lg = l >> 4;

    // ---- W fragments (A operand: row = o = nf*16+lr, k = ki*32+lg*8+j), once ----
    bf16x8 bfr[4][2];
    #pragma unroll
    for (int nf = 0; nf < 4; ++nf)
        #pragma unroll
        for (int ki = 0; ki < 2; ++ki)
            bfr[nf][ki] = *(const bf16x8*)(&wtl[(nf * 16 + lr) * LDW + ki * 32 + lg * 8]);

    // ---- coef slice for this lane's k slots, once ----
    const float* cp = coef + n * 32 + lg * 8;
    float c[8];
    #pragma unroll
    for (int jj = 0; jj < 8; ++jj) c[jj] = cp[jj];

    // ---- bias (o = nf*16 + lg*4 + q), once ----
    const float* bn = bias + n * 64;
    f32x4 bv[4];
    #pragma unroll
    for (int nf = 0; nf < 4; ++nf)
        bv[nf] = *(const f32x4*)(bn + nf * 16 + lg * 4);

    // ---- per-tile: x load -> sincos -> MFMA -> store ----
    for (int tt = 0; tt < TILES; ++tt) {
        const int b0   = b_base + tt * BM;
        const int row0 = b0 + w * 32 + lr;
        const float x0 = x[row0 * N + n];
        const float x1 = x[(row0 + 16) * N + n];

        // emb fragments (B operand: col = out-block row = lr, k = lg*8+j)
        bf16x8 a_s[2], a_c[2];
        #pragma unroll
        for (int m = 0; m < 2; ++m) {
            float xv = m ? x1 : x0;
            #pragma unroll
            for (int jj = 0; jj < 8; ++jj) {
                float v = c[jj] * xv;
                v = __builtin_amdgcn_fractf(v);            // sin(2*pi*t)=v_sin(fract(t))
                a_s[m][jj] = f2bf(__builtin_amdgcn_sinf(v));
                a_c[m][jj] = f2bf(__builtin_amdgcn_cosf(v));
            }
        }

        // D = W x emb: D row = o (4 consecutive per lane), D col = b-row
        f32x4 acc[2][4];
        #pragma unroll
        for (int m = 0; m < 2; ++m)
            #pragma unroll
            for (int nf = 0; nf < 4; ++nf) {
                f32x4 z = {0.f, 0.f, 0.f, 0.f};
                z = __builtin_amdgcn_mfma_f32_16x16x32_bf16(bfr[nf][0], a_s[m], z, 0, 0, 0);
                z = __builtin_amdgcn_mfma_f32_16x16x32_bf16(bfr[nf][1], a_c[m], z, 0, 0, 0);
                acc[m][nf] = z;
            }

        // epilogue: +bias, relu, float4 stores (o = nf*16 + lg*4 + q contiguous)
        #pragma unroll
        for (int m = 0; m < 2; ++m) {
            int row = b0 + w * 32 + m * 16 + lr;
            float* op = out + (size_t)row * 16384 + n * 64 + lg * 4;
            #pragma unroll
            for (int nf = 0; nf < 4; ++nf) {
                f32x4 v = acc[m][nf] + bv[nf];
                f32x4 r;
                #pragma unroll
                for (int q = 0; q < 4; ++q) r[q] = fmaxf(v[q], 0.0f);
                *(f32x4*)(op + nf * 16) = r;
            }
        }
    }
}

extern "C" void kernel_launch(void* const* d_in, const int* in_sizes, int n_in,
                              void* d_out, int out_size, void* d_ws, size_t ws_size,
                              hipStream_t stream) {
    const float* x    = (const float*)d_in[0];
    const float* coef = (const float*)d_in[1];
    const float* wgt  = (const float*)d_in[2];
    const float* bias = (const float*)d_in[3];
    float* out = (float*)d_out;

    dim3 grid(256 * (8192 / (BM * TILES)));   // 4096 blocks
    dim3 block(256);
    hipLaunchKernelGGL(pe_kernel, grid, block, 0, stream,
                       x, coef, wgt, bias, out);
}